// Round 4
// baseline (435.306 us; speedup 1.0000x reference)
//
#include <hip/hip_runtime.h>
#include <hip/hip_bf16.h>
#include <math.h>

typedef __hip_bfloat16 bf16;
typedef __attribute__((ext_vector_type(8))) short short8;
typedef __attribute__((ext_vector_type(4))) float floatx4;
typedef __attribute__((ext_vector_type(16))) float floatx16;

__device__ __forceinline__ void async_copy16(const void* gptr, void* lptr) {
  __builtin_amdgcn_global_load_lds(
      (const __attribute__((address_space(1))) unsigned int*)gptr,
      (__attribute__((address_space(3))) unsigned int*)lptr,
      16, 0, 0);
}

__device__ __forceinline__ unsigned int f2bf_bits(float x) {
  bf16 h = __float2bfloat16(x);
  return (unsigned int)*reinterpret_cast<unsigned short*>(&h);
}

__device__ __forceinline__ float bfbits2f(unsigned int u) {
  unsigned v = u << 16;
  return *reinterpret_cast<float*>(&v);
}

__device__ __forceinline__ floatx4 mfma16(short8 a, short8 b, floatx4 c) {
  return __builtin_amdgcn_mfma_f32_16x16x32_bf16(a, b, c, 0, 0, 0);
}

// flag = 1 -> fp32 inputs, 0 -> bf16 inputs.
__global__ void dtype_sniff(const unsigned int* __restrict__ u, int* __restrict__ flag) {
  __shared__ int cnt[256];
  const int tid = threadIdx.x;
  const unsigned v = u[tid * 16];
  const int e = (v >> 7) & 0xFF;
  cnt[tid] = (e >= 90 && e <= 140) ? 1 : 0;
  __syncthreads();
  for (int s = 128; s > 0; s >>= 1) {
    if (tid < s) cnt[tid] += cnt[tid + s];
    __syncthreads();
  }
  if (tid == 0) flag[0] = (cnt[0] >= 192) ? 0 : 1;
}

// One kernel converting all inputs to bf16 (fp32 src if *flag else bf16 copy).
__global__ void conv_all(const void* hs, const void* wq, const void* wk, const void* wv,
                         const void* wo, const void* bq, const void* bk, const void* bv,
                         bf16* hsb, bf16* wqb, bf16* wkb, bf16* wvb, bf16* wob, bf16* b3,
                         long nhs4, const int* __restrict__ flag) {
  const bool f = (*flag != 0);
  const long W4 = 1048576, KV4 = 262144;  // H*H/4, KV*H/4
  const long total = nhs4 + W4 + 2 * KV4 + W4 + 512 + 128 + 128;
  const long stride = (long)gridDim.x * blockDim.x;
  for (long i = (long)blockIdx.x * blockDim.x + threadIdx.x; i < total; i += stride) {
    const void* src;
    bf16* dst;
    long off, j = i;
    if (j < nhs4) { src = hs; dst = hsb; off = j; }
    else if ((j -= nhs4) < W4) { src = wq; dst = wqb; off = j; }
    else if ((j -= W4) < KV4) { src = wk; dst = wkb; off = j; }
    else if ((j -= KV4) < KV4) { src = wv; dst = wvb; off = j; }
    else if ((j -= KV4) < W4) { src = wo; dst = wob; off = j; }
    else if ((j -= W4) < 512) { src = bq; dst = b3; off = j; }
    else if ((j -= 512) < 128) { src = bk; dst = b3 + 2048; off = j; }
    else { j -= 128; src = bv; dst = b3 + 2560; off = j; }
    uint2 o;
    if (f) {
      float4 v = ((const float4*)src)[off];
      o.x = f2bf_bits(v.x) | (f2bf_bits(v.y) << 16);
      o.y = f2bf_bits(v.z) | (f2bf_bits(v.w) << 16);
    } else {
      o = ((const uint2*)src)[off];
    }
    ((uint2*)dst)[off] = o;
  }
}

// Fused QKV GEMM (m97 structure).  Q->Qb [M,2048], K->Kb [M,512],
// V->Vt [B,4,128,S] transposed.  bias3 = bq|bk|bv.
__global__ __launch_bounds__(256) void qkv_gemm(const bf16* __restrict__ A,
                                                const bf16* __restrict__ wq,
                                                const bf16* __restrict__ wk,
                                                const bf16* __restrict__ wv,
                                                const bf16* __restrict__ bias3,
                                                bf16* __restrict__ Qb,
                                                bf16* __restrict__ Kb,
                                                bf16* __restrict__ Vt,
                                                int M, int K, int S) {
  __shared__ __align__(16) short lA[128 * 32];
  __shared__ __align__(16) short lB[128 * 32];
  const int tid = threadIdx.x;
  const int wave = tid >> 6;
  const int lane = tid & 63;
  const int lrow = lane & 15;
  const int quad = lane >> 4;
  const int m0 = blockIdx.y * 128;
  const int n0 = blockIdx.x * 128;
  const int wm = (wave & 1) * 64;
  const int wn = (wave >> 1) * 64;
  const int sr = tid >> 2;
  const int sc = (tid & 3) * 8;

  const bf16* Wr;
  int nloc;
  if (n0 < 2048) { Wr = wq; nloc = n0; }
  else if (n0 < 2560) { Wr = wk; nloc = n0 - 2048; }
  else { Wr = wv; nloc = n0 - 2560; }

  floatx4 acc[4][4] = {};
  for (int k0 = 0; k0 < K; k0 += 32) {
#pragma unroll
    for (int it = 0; it < 2; ++it) {
      async_copy16(A + (size_t)(m0 + it * 64 + sr) * K + k0 + sc,
                   &lA[it * 2048 + wave * 512]);
      async_copy16(Wr + (size_t)(nloc + it * 64 + sr) * K + k0 + sc,
                   &lB[it * 2048 + wave * 512]);
    }
    __syncthreads();
    short8 af[4], bf[4];
#pragma unroll
    for (int i = 0; i < 4; ++i)
      af[i] = *(const short8*)&lA[(wm + i * 16 + lrow) * 32 + quad * 8];
#pragma unroll
    for (int j = 0; j < 4; ++j)
      bf[j] = *(const short8*)&lB[(wn + j * 16 + lrow) * 32 + quad * 8];
#pragma unroll
    for (int i = 0; i < 4; ++i)
#pragma unroll
      for (int j = 0; j < 4; ++j)
        acc[i][j] = mfma16(af[i], bf[j], acc[i][j]);
    __syncthreads();
  }

#pragma unroll
  for (int j = 0; j < 4; ++j) {
    const int col = n0 + wn + j * 16 + lrow;
    const float bv = __bfloat162float(bias3[col]);
#pragma unroll
    for (int i = 0; i < 4; ++i) {
      const int row = m0 + wm + i * 16 + quad * 4;
      if (n0 < 2048) {
#pragma unroll
        for (int r = 0; r < 4; ++r)
          Qb[(size_t)(row + r) * 2048 + col] = __float2bfloat16(acc[i][j][r] + bv);
      } else if (n0 < 2560) {
#pragma unroll
        for (int r = 0; r < 4; ++r)
          Kb[(size_t)(row + r) * 512 + (col - 2048)] = __float2bfloat16(acc[i][j][r] + bv);
      } else {
        const int dcol = col - 2560;
        const int kvh = dcol >> 7, d = dcol & 127;
        const int bb = row / S, s = row % S;
        uint2 pk;
        pk.x = f2bf_bits(acc[i][j][0] + bv) | (f2bf_bits(acc[i][j][1] + bv) << 16);
        pk.y = f2bf_bits(acc[i][j][2] + bv) | (f2bf_bits(acc[i][j][3] + bv) << 16);
        *(uint2*)&Vt[((size_t)(bb * 4 + kvh) * 128 + d) * S + s] = pk;
      }
    }
  }
}

// O-proj GEMM: out fp32 if *flag else bf16.
__global__ __launch_bounds__(256) void gemm_o(const bf16* __restrict__ A,
                                              const bf16* __restrict__ W,
                                              void* __restrict__ C,
                                              int M, int N, int K,
                                              const int* __restrict__ flag) {
  __shared__ __align__(16) short lA[128 * 32];
  __shared__ __align__(16) short lB[128 * 32];
  const int tid = threadIdx.x;
  const int wave = tid >> 6;
  const int lane = tid & 63;
  const int lrow = lane & 15;
  const int quad = lane >> 4;
  const int m0 = blockIdx.y * 128;
  const int n0 = blockIdx.x * 128;
  const int wm = (wave & 1) * 64;
  const int wn = (wave >> 1) * 64;
  const int sr = tid >> 2;
  const int sc = (tid & 3) * 8;
  const bool of32 = (*flag != 0);

  floatx4 acc[4][4] = {};
  for (int k0 = 0; k0 < K; k0 += 32) {
#pragma unroll
    for (int it = 0; it < 2; ++it) {
      async_copy16(A + (size_t)(m0 + it * 64 + sr) * K + k0 + sc,
                   &lA[it * 2048 + wave * 512]);
      async_copy16(W + (size_t)(n0 + it * 64 + sr) * K + k0 + sc,
                   &lB[it * 2048 + wave * 512]);
    }
    __syncthreads();
    short8 af[4], bf[4];
#pragma unroll
    for (int i = 0; i < 4; ++i)
      af[i] = *(const short8*)&lA[(wm + i * 16 + lrow) * 32 + quad * 8];
#pragma unroll
    for (int j = 0; j < 4; ++j)
      bf[j] = *(const short8*)&lB[(wn + j * 16 + lrow) * 32 + quad * 8];
#pragma unroll
    for (int i = 0; i < 4; ++i)
#pragma unroll
      for (int j = 0; j < 4; ++j)
        acc[i][j] = mfma16(af[i], bf[j], acc[i][j]);
    __syncthreads();
  }

#pragma unroll
  for (int j = 0; j < 4; ++j) {
    const int col = n0 + wn + j * 16 + lrow;
#pragma unroll
    for (int i = 0; i < 4; ++i) {
      const int row = m0 + wm + i * 16 + quad * 4;
#pragma unroll
      for (int r = 0; r < 4; ++r) {
        const size_t idx = (size_t)(row + r) * N + col;
        if (of32) ((float*)C)[idx] = acc[i][j][r];
        else ((bf16*)C)[idx] = __float2bfloat16(acc[i][j][r]);
      }
    }
  }
}

// Vectorized in-place RoPE.  One block per token; Q: 16 heads x 16 d-quads,
// K: heads 0..3.
__global__ __launch_bounds__(256) void rope_kernel(bf16* __restrict__ Qb,
                                                   bf16* __restrict__ Kb,
                                                   const int* __restrict__ pos_ids) {
  const int token = blockIdx.x;
  const int tid = threadIdx.x;
  const float pos = (float)pos_ids[token];
  const int hh = tid >> 4;
  const int i4 = (tid & 15) * 4;
  float cs[4], sn[4];
#pragma unroll
  for (int e = 0; e < 4; ++e) {
    const float freq = exp2f((float)(i4 + e) * -0.31143075889569023f);
    const float ang = pos * freq;
    __sincosf(ang, &sn[e], &cs[e]);
  }
  {
    bf16* qp = Qb + (size_t)token * 2048 + hh * 128 + i4;
    uint2 lo = *(uint2*)qp, hi = *(uint2*)(qp + 64);
    unsigned lol[4] = {lo.x & 0xffff, lo.x >> 16, lo.y & 0xffff, lo.y >> 16};
    unsigned hil[4] = {hi.x & 0xffff, hi.x >> 16, hi.y & 0xffff, hi.y >> 16};
    uint2 olo, ohi;
    unsigned t[4], u[4];
#pragma unroll
    for (int e = 0; e < 4; ++e) {
      const float l = bfbits2f(lol[e]), h = bfbits2f(hil[e]);
      t[e] = f2bf_bits(l * cs[e] - h * sn[e]);
      u[e] = f2bf_bits(h * cs[e] + l * sn[e]);
    }
    olo.x = t[0] | (t[1] << 16); olo.y = t[2] | (t[3] << 16);
    ohi.x = u[0] | (u[1] << 16); ohi.y = u[2] | (u[3] << 16);
    *(uint2*)qp = olo;
    *(uint2*)(qp + 64) = ohi;
  }
  if (hh < 4) {
    bf16* kp = Kb + (size_t)token * 512 + hh * 128 + i4;
    uint2 lo = *(uint2*)kp, hi = *(uint2*)(kp + 64);
    unsigned lol[4] = {lo.x & 0xffff, lo.x >> 16, lo.y & 0xffff, lo.y >> 16};
    unsigned hil[4] = {hi.x & 0xffff, hi.x >> 16, hi.y & 0xffff, hi.y >> 16};
    uint2 olo, ohi;
    unsigned t[4], u[4];
#pragma unroll
    for (int e = 0; e < 4; ++e) {
      const float l = bfbits2f(lol[e]), h = bfbits2f(hil[e]);
      t[e] = f2bf_bits(l * cs[e] - h * sn[e]);
      u[e] = f2bf_bits(h * cs[e] + l * sn[e]);
    }
    olo.x = t[0] | (t[1] << 16); olo.y = t[2] | (t[3] << 16);
    ohi.x = u[0] | (u[1] << 16); ohi.y = u[2] | (u[3] << 16);
    *(uint2*)kp = olo;
    *(uint2*)(kp + 64) = ohi;
  }
}

// Flash attention, 32x32x16 MFMA, S^T / O^T orientation.
// Block = 128 q-rows x one (b,h); 4 waves, wave owns 32 q-cols.  BKV=64.
// K/V staged in fragment order (conflict-free lane*16 reads).
// Q resident in registers (B-operand).  O aliases Q (reads precede writes).
__global__ __launch_bounds__(256, 3) void flash_attn(const bf16* Q,
                                                     const bf16* __restrict__ K,
                                                     const bf16* __restrict__ Vt,
                                                     bf16* O, int S) {
  __shared__ __align__(16) short lK[16 * 512];  // frag fk=kstep*2+mt: K[kv=mt*32+l31][d=kstep*16+half*8+j]
  __shared__ __align__(16) short lV[16 * 512];  // frag fv=kvs*4+mtd: Vt[d=mtd*32+l31][kv=kvs*16+half*8+j]
  __shared__ __align__(16) short lP[4 * 2048];  // per-wave [32 q][64 kv], chunk-xor-swizzled

  const int tid = threadIdx.x;
  const int wave = tid >> 6;
  const int lane = tid & 63;
  const int l31 = lane & 31;
  const int half = lane >> 5;
  const int bh = blockIdx.x;
  const int qt = (gridDim.y - 1) - blockIdx.y;  // LPT: longest first
  const int q0 = qt * 128;
  const int b = bh >> 4;
  const int h = bh & 15;
  const int kvh = h >> 2;
  const int wq0 = wave * 32;
  const int q_g = q0 + wq0 + l31;

  // Q fragments in registers (B-operand): qf[ks] = Q[q_g][d=ks*16+half*8+j]
  short8 qf[8];
  {
    const bf16* qbase = Q + ((size_t)(b * S + q_g) * 16 + h) * 128 + half * 8;
#pragma unroll
    for (int ks = 0; ks < 8; ++ks)
      qf[ks] = *(const short8*)(qbase + ks * 16);
  }

  floatx16 acc[4] = {};
  float m_i = -1.0e30f, l_i = 0.0f;
  const float scale = 0.08838834764831845f;
  const int fk0 = wave * 4;
  short* lPw = &lP[wave * 2048];
  const int sw = l31 & 7;

  const int niter = 2 * qt + 2;
  int kv0 = 0;
  for (int it = 0; it < niter; ++it, kv0 += 64) {
    __syncthreads();  // prev iter's lK/lV reads done
#pragma unroll
    for (int i = 0; i < 4; ++i) {
      const int fk = fk0 + i;
      const int mt = fk & 1, kstep = fk >> 1;
      async_copy16(K + ((size_t)(b * S + kv0 + mt * 32 + l31) * 4 + kvh) * 128 + kstep * 16 + half * 8,
                   &lK[fk * 512]);
      const int kvs = fk >> 2, mtd = fk & 3;
      async_copy16(Vt + ((size_t)(b * 4 + kvh) * 128 + mtd * 32 + l31) * S + kv0 + kvs * 16 + half * 8,
                   &lV[fk * 512]);
    }
    __syncthreads();  // staging visible

    // S^T = K·Q^T  (C: col = q = l31, row = kv = mt*32 + (r&3)+8*(r>>2)+4*half)
    floatx16 st[2] = {};
#pragma unroll
    for (int ks = 0; ks < 8; ++ks) {
      short8 k0 = *(const short8*)&lK[(ks * 2 + 0) * 512 + lane * 8];
      short8 k1 = *(const short8*)&lK[(ks * 2 + 1) * 512 + lane * 8];
      st[0] = __builtin_amdgcn_mfma_f32_32x32x16_bf16(k0, qf[ks], st[0], 0, 0, 0);
      st[1] = __builtin_amdgcn_mfma_f32_32x32x16_bf16(k1, qf[ks], st[1], 0, 0, 0);
    }

    // scale + causal mask + per-lane softmax (1 shfl per reduction)
    float mx = -1.0e30f;
    if (kv0 + 63 > q0 + wq0) {
#pragma unroll
      for (int r = 0; r < 16; ++r) {
        const int kv_l = kv0 + (r & 3) + 8 * (r >> 2) + 4 * half;
        float v0 = st[0][r] * scale;
        v0 = (kv_l > q_g) ? -1.0e9f : v0;
        float v1 = st[1][r] * scale;
        v1 = (kv_l + 32 > q_g) ? -1.0e9f : v1;
        st[0][r] = v0; st[1][r] = v1;
        mx = fmaxf(mx, fmaxf(v0, v1));
      }
    } else {
#pragma unroll
      for (int r = 0; r < 16; ++r) {
        const float v0 = st[0][r] * scale;
        const float v1 = st[1][r] * scale;
        st[0][r] = v0; st[1][r] = v1;
        mx = fmaxf(mx, fmaxf(v0, v1));
      }
    }
    mx = fmaxf(mx, __shfl_xor(mx, 32));
    const float mnew = fmaxf(m_i, mx);
    const float alpha = __expf(m_i - mnew);
    m_i = mnew;
    float rs = 0.0f;
#pragma unroll
    for (int r = 0; r < 16; ++r) {
      const float p0 = __expf(st[0][r] - mnew);
      const float p1 = __expf(st[1][r] - mnew);
      st[0][r] = p0; st[1][r] = p1;
      rs += p0 + p1;
    }
    rs += __shfl_xor(rs, 32);
    l_i = l_i * alpha + rs;
#pragma unroll
    for (int t = 0; t < 4; ++t)
#pragma unroll
      for (int r = 0; r < 16; ++r) acc[t][r] *= alpha;

    // P -> lPw (wave-private; regs 4g..4g+3 -> kv = mt*32+8g+4*half+{0..3})
#pragma unroll
    for (int g = 0; g < 4; ++g) {
      uint2 p0, p1;
      p0.x = f2bf_bits(st[0][4 * g]) | (f2bf_bits(st[0][4 * g + 1]) << 16);
      p0.y = f2bf_bits(st[0][4 * g + 2]) | (f2bf_bits(st[0][4 * g + 3]) << 16);
      p1.x = f2bf_bits(st[1][4 * g]) | (f2bf_bits(st[1][4 * g + 1]) << 16);
      p1.y = f2bf_bits(st[1][4 * g + 2]) | (f2bf_bits(st[1][4 * g + 3]) << 16);
      *(uint2*)&lPw[l31 * 64 + (g ^ sw) * 8 + half * 4] = p0;
      *(uint2*)&lPw[l31 * 64 + ((4 + g) ^ sw) * 8 + half * 4] = p1;
    }

    // O^T += V^T·P^T  (A = V frag, B = P frag; C: col = q = l31, rows = d)
#pragma unroll
    for (int kvs = 0; kvs < 4; ++kvs) {
      const int ckr = kvs * 2 + half;
      short8 pf = *(const short8*)&lPw[l31 * 64 + (ckr ^ sw) * 8];
#pragma unroll
      for (int mtd = 0; mtd < 4; ++mtd) {
        short8 vf = *(const short8*)&lV[(kvs * 4 + mtd) * 512 + lane * 8];
        acc[mtd] = __builtin_amdgcn_mfma_f32_32x32x16_bf16(vf, pf, acc[mtd], 0, 0, 0);
      }
    }
  }

  // epilogue: lane owns q-col; d rows = mtd*32 + 8g + 4*half + {0..3}
  const float inv_l = 1.0f / l_i;
  bf16* obase = O + ((size_t)(b * S + q_g) * 16 + h) * 128;
#pragma unroll
  for (int mtd = 0; mtd < 4; ++mtd)
#pragma unroll
    for (int g = 0; g < 4; ++g) {
      uint2 pk;
      pk.x = f2bf_bits(acc[mtd][4 * g] * inv_l) | (f2bf_bits(acc[mtd][4 * g + 1] * inv_l) << 16);
      pk.y = f2bf_bits(acc[mtd][4 * g + 2] * inv_l) | (f2bf_bits(acc[mtd][4 * g + 3] * inv_l) << 16);
      *(uint2*)(obase + mtd * 32 + 8 * g + 4 * half) = pk;
    }
}

extern "C" void kernel_launch(void* const* d_in, const int* in_sizes, int n_in,
                              void* d_out, int out_size, void* d_ws, size_t ws_size,
                              hipStream_t stream) {
  const void* hs = d_in[0];
  const void* wq = d_in[1];
  const void* bq = d_in[2];
  const void* wk = d_in[3];
  const void* bk = d_in[4];
  const void* wv = d_in[5];
  const void* bv = d_in[6];
  const void* wo = d_in[7];
  const int* pos = (const int*)d_in[8];

  const int S = 2048, H = 2048, KV = 512;
  const int B = in_sizes[0] / (S * H);
  const int M = B * S;

  char* ws = (char*)d_ws;
  size_t off = 0;
  auto alloc = [&](size_t bytes) { char* p = ws + off; off += (bytes + 255) & ~(size_t)255; return p; };
  bf16* hsb = (bf16*)alloc((size_t)M * H * 2);
  bf16* wqb = (bf16*)alloc((size_t)H * H * 2);
  bf16* wkb = (bf16*)alloc((size_t)KV * H * 2);
  bf16* wvb = (bf16*)alloc((size_t)KV * H * 2);
  bf16* wob = (bf16*)alloc((size_t)H * H * 2);
  bf16* bias3 = (bf16*)alloc(3072 * 2);
  bf16* Qb = (bf16*)alloc((size_t)M * H * 2);
  bf16* Kb = (bf16*)alloc((size_t)M * KV * 2);
  bf16* Vt = (bf16*)alloc((size_t)M * KV * 2);
  int* flag = (int*)alloc(256);
  bf16* AO = Qb;  // flash writes O over its own Q rows (disjoint per block)

  dtype_sniff<<<1, 256, 0, stream>>>((const unsigned int*)hs, flag);
  conv_all<<<2048, 256, 0, stream>>>(hs, wq, wk, wv, wo, bq, bk, bv,
                                     hsb, wqb, wkb, wvb, wob, bias3,
                                     (long)M * H / 4, flag);
  qkv_gemm<<<dim3(24, M / 128), 256, 0, stream>>>(hsb, wqb, wkb, wvb, bias3,
                                                  Qb, Kb, Vt, M, H, S);
  rope_kernel<<<M, 256, 0, stream>>>(Qb, Kb, pos);
  flash_attn<<<dim3(B * 16, S / 128), 256, 0, stream>>>(Qb, Kb, Vt, AO, S);
  gemm_o<<<dim3(H / 128, M / 128), 256, 0, stream>>>(AO, wob, d_out, M, H, H, flag);
}

// Round 5
// 352.286 us; speedup vs baseline: 1.2357x; 1.2357x over previous
//
#include <hip/hip_runtime.h>
#include <hip/hip_bf16.h>
#include <math.h>

typedef __hip_bfloat16 bf16;
typedef __attribute__((ext_vector_type(8))) short short8;
typedef __attribute__((ext_vector_type(4))) float floatx4;
typedef __attribute__((ext_vector_type(16))) float floatx16;

__device__ __forceinline__ void async_copy16(const void* gptr, void* lptr) {
  __builtin_amdgcn_global_load_lds(
      (const __attribute__((address_space(1))) unsigned int*)gptr,
      (__attribute__((address_space(3))) unsigned int*)lptr,
      16, 0, 0);
}

__device__ __forceinline__ unsigned int f2bf_bits(float x) {
  bf16 h = __float2bfloat16(x);
  return (unsigned int)*reinterpret_cast<unsigned short*>(&h);
}

__device__ __forceinline__ float bfbits2f(unsigned int u) {
  unsigned v = u << 16;
  return *reinterpret_cast<float*>(&v);
}

__device__ __forceinline__ floatx4 mfma16(short8 a, short8 b, floatx4 c) {
  return __builtin_amdgcn_mfma_f32_16x16x32_bf16(a, b, c, 0, 0, 0);
}

// flag = 1 -> fp32 inputs, 0 -> bf16 inputs.
__global__ void dtype_sniff(const unsigned int* __restrict__ u, int* __restrict__ flag) {
  __shared__ int cnt[256];
  const int tid = threadIdx.x;
  const unsigned v = u[tid * 16];
  const int e = (v >> 7) & 0xFF;
  cnt[tid] = (e >= 90 && e <= 140) ? 1 : 0;
  __syncthreads();
  for (int s = 128; s > 0; s >>= 1) {
    if (tid < s) cnt[tid] += cnt[tid + s];
    __syncthreads();
  }
  if (tid == 0) flag[0] = (cnt[0] >= 192) ? 0 : 1;
}

// One kernel converting all inputs to bf16 (fp32 src if *flag else bf16 copy).
__global__ void conv_all(const void* hs, const void* wq, const void* wk, const void* wv,
                         const void* wo, const void* bq, const void* bk, const void* bv,
                         bf16* hsb, bf16* wqb, bf16* wkb, bf16* wvb, bf16* wob, bf16* b3,
                         long nhs4, const int* __restrict__ flag) {
  const bool f = (*flag != 0);
  const long W4 = 1048576, KV4 = 262144;  // H*H/4, KV*H/4
  const long total = nhs4 + W4 + 2 * KV4 + W4 + 512 + 128 + 128;
  const long stride = (long)gridDim.x * blockDim.x;
  for (long i = (long)blockIdx.x * blockDim.x + threadIdx.x; i < total; i += stride) {
    const void* src;
    bf16* dst;
    long off, j = i;
    if (j < nhs4) { src = hs; dst = hsb; off = j; }
    else if ((j -= nhs4) < W4) { src = wq; dst = wqb; off = j; }
    else if ((j -= W4) < KV4) { src = wk; dst = wkb; off = j; }
    else if ((j -= KV4) < KV4) { src = wv; dst = wvb; off = j; }
    else if ((j -= KV4) < W4) { src = wo; dst = wob; off = j; }
    else if ((j -= W4) < 512) { src = bq; dst = b3; off = j; }
    else if ((j -= 512) < 128) { src = bk; dst = b3 + 2048; off = j; }
    else { j -= 128; src = bv; dst = b3 + 2560; off = j; }
    uint2 o;
    if (f) {
      float4 v = ((const float4*)src)[off];
      o.x = f2bf_bits(v.x) | (f2bf_bits(v.y) << 16);
      o.y = f2bf_bits(v.z) | (f2bf_bits(v.w) << 16);
    } else {
      o = ((const uint2*)src)[off];
    }
    ((uint2*)dst)[off] = o;
  }
}

// Fused QKV GEMM (m97 structure).  Q->Qb [M,2048], K->Kb [M,512],
// V->Vt [B,4,128,S] transposed.  bias3 = bq|bk|bv.
__global__ __launch_bounds__(256) void qkv_gemm(const bf16* __restrict__ A,
                                                const bf16* __restrict__ wq,
                                                const bf16* __restrict__ wk,
                                                const bf16* __restrict__ wv,
                                                const bf16* __restrict__ bias3,
                                                bf16* __restrict__ Qb,
                                                bf16* __restrict__ Kb,
                                                bf16* __restrict__ Vt,
                                                int M, int K, int S) {
  __shared__ __align__(16) short lA[128 * 32];
  __shared__ __align__(16) short lB[128 * 32];
  const int tid = threadIdx.x;
  const int wave = tid >> 6;
  const int lane = tid & 63;
  const int lrow = lane & 15;
  const int quad = lane >> 4;
  const int m0 = blockIdx.y * 128;
  const int n0 = blockIdx.x * 128;
  const int wm = (wave & 1) * 64;
  const int wn = (wave >> 1) * 64;
  const int sr = tid >> 2;
  const int sc = (tid & 3) * 8;

  const bf16* Wr;
  int nloc;
  if (n0 < 2048) { Wr = wq; nloc = n0; }
  else if (n0 < 2560) { Wr = wk; nloc = n0 - 2048; }
  else { Wr = wv; nloc = n0 - 2560; }

  floatx4 acc[4][4] = {};
  for (int k0 = 0; k0 < K; k0 += 32) {
#pragma unroll
    for (int it = 0; it < 2; ++it) {
      async_copy16(A + (size_t)(m0 + it * 64 + sr) * K + k0 + sc,
                   &lA[it * 2048 + wave * 512]);
      async_copy16(Wr + (size_t)(nloc + it * 64 + sr) * K + k0 + sc,
                   &lB[it * 2048 + wave * 512]);
    }
    __syncthreads();
    short8 af[4], bf[4];
#pragma unroll
    for (int i = 0; i < 4; ++i)
      af[i] = *(const short8*)&lA[(wm + i * 16 + lrow) * 32 + quad * 8];
#pragma unroll
    for (int j = 0; j < 4; ++j)
      bf[j] = *(const short8*)&lB[(wn + j * 16 + lrow) * 32 + quad * 8];
#pragma unroll
    for (int i = 0; i < 4; ++i)
#pragma unroll
      for (int j = 0; j < 4; ++j)
        acc[i][j] = mfma16(af[i], bf[j], acc[i][j]);
    __syncthreads();
  }

#pragma unroll
  for (int j = 0; j < 4; ++j) {
    const int col = n0 + wn + j * 16 + lrow;
    const float bv = __bfloat162float(bias3[col]);
#pragma unroll
    for (int i = 0; i < 4; ++i) {
      const int row = m0 + wm + i * 16 + quad * 4;
      if (n0 < 2048) {
#pragma unroll
        for (int r = 0; r < 4; ++r)
          Qb[(size_t)(row + r) * 2048 + col] = __float2bfloat16(acc[i][j][r] + bv);
      } else if (n0 < 2560) {
#pragma unroll
        for (int r = 0; r < 4; ++r)
          Kb[(size_t)(row + r) * 512 + (col - 2048)] = __float2bfloat16(acc[i][j][r] + bv);
      } else {
        const int dcol = col - 2560;
        const int kvh = dcol >> 7, d = dcol & 127;
        const int bb = row / S, s = row % S;
        uint2 pk;
        pk.x = f2bf_bits(acc[i][j][0] + bv) | (f2bf_bits(acc[i][j][1] + bv) << 16);
        pk.y = f2bf_bits(acc[i][j][2] + bv) | (f2bf_bits(acc[i][j][3] + bv) << 16);
        *(uint2*)&Vt[((size_t)(bb * 4 + kvh) * 128 + d) * S + s] = pk;
      }
    }
  }
}

// O-proj GEMM: out fp32 if *flag else bf16.
__global__ __launch_bounds__(256) void gemm_o(const bf16* __restrict__ A,
                                              const bf16* __restrict__ W,
                                              void* __restrict__ C,
                                              int M, int N, int K,
                                              const int* __restrict__ flag) {
  __shared__ __align__(16) short lA[128 * 32];
  __shared__ __align__(16) short lB[128 * 32];
  const int tid = threadIdx.x;
  const int wave = tid >> 6;
  const int lane = tid & 63;
  const int lrow = lane & 15;
  const int quad = lane >> 4;
  const int m0 = blockIdx.y * 128;
  const int n0 = blockIdx.x * 128;
  const int wm = (wave & 1) * 64;
  const int wn = (wave >> 1) * 64;
  const int sr = tid >> 2;
  const int sc = (tid & 3) * 8;
  const bool of32 = (*flag != 0);

  floatx4 acc[4][4] = {};
  for (int k0 = 0; k0 < K; k0 += 32) {
#pragma unroll
    for (int it = 0; it < 2; ++it) {
      async_copy16(A + (size_t)(m0 + it * 64 + sr) * K + k0 + sc,
                   &lA[it * 2048 + wave * 512]);
      async_copy16(W + (size_t)(n0 + it * 64 + sr) * K + k0 + sc,
                   &lB[it * 2048 + wave * 512]);
    }
    __syncthreads();
    short8 af[4], bf[4];
#pragma unroll
    for (int i = 0; i < 4; ++i)
      af[i] = *(const short8*)&lA[(wm + i * 16 + lrow) * 32 + quad * 8];
#pragma unroll
    for (int j = 0; j < 4; ++j)
      bf[j] = *(const short8*)&lB[(wn + j * 16 + lrow) * 32 + quad * 8];
#pragma unroll
    for (int i = 0; i < 4; ++i)
#pragma unroll
      for (int j = 0; j < 4; ++j)
        acc[i][j] = mfma16(af[i], bf[j], acc[i][j]);
    __syncthreads();
  }

#pragma unroll
  for (int j = 0; j < 4; ++j) {
    const int col = n0 + wn + j * 16 + lrow;
#pragma unroll
    for (int i = 0; i < 4; ++i) {
      const int row = m0 + wm + i * 16 + quad * 4;
#pragma unroll
      for (int r = 0; r < 4; ++r) {
        const size_t idx = (size_t)(row + r) * N + col;
        if (of32) ((float*)C)[idx] = acc[i][j][r];
        else ((bf16*)C)[idx] = __float2bfloat16(acc[i][j][r]);
      }
    }
  }
}

// Vectorized in-place RoPE.  One block per token.
__global__ __launch_bounds__(256) void rope_kernel(bf16* __restrict__ Qb,
                                                   bf16* __restrict__ Kb,
                                                   const int* __restrict__ pos_ids) {
  const int token = blockIdx.x;
  const int tid = threadIdx.x;
  const float pos = (float)pos_ids[token];
  const int hh = tid >> 4;
  const int i4 = (tid & 15) * 4;
  float cs[4], sn[4];
#pragma unroll
  for (int e = 0; e < 4; ++e) {
    const float freq = exp2f((float)(i4 + e) * -0.31143075889569023f);
    const float ang = pos * freq;
    __sincosf(ang, &sn[e], &cs[e]);
  }
  {
    bf16* qp = Qb + (size_t)token * 2048 + hh * 128 + i4;
    uint2 lo = *(uint2*)qp, hi = *(uint2*)(qp + 64);
    unsigned lol[4] = {lo.x & 0xffff, lo.x >> 16, lo.y & 0xffff, lo.y >> 16};
    unsigned hil[4] = {hi.x & 0xffff, hi.x >> 16, hi.y & 0xffff, hi.y >> 16};
    uint2 olo, ohi;
    unsigned t[4], u[4];
#pragma unroll
    for (int e = 0; e < 4; ++e) {
      const float l = bfbits2f(lol[e]), h = bfbits2f(hil[e]);
      t[e] = f2bf_bits(l * cs[e] - h * sn[e]);
      u[e] = f2bf_bits(h * cs[e] + l * sn[e]);
    }
    olo.x = t[0] | (t[1] << 16); olo.y = t[2] | (t[3] << 16);
    ohi.x = u[0] | (u[1] << 16); ohi.y = u[2] | (u[3] << 16);
    *(uint2*)qp = olo;
    *(uint2*)(qp + 64) = ohi;
  }
  if (hh < 4) {
    bf16* kp = Kb + (size_t)token * 512 + hh * 128 + i4;
    uint2 lo = *(uint2*)kp, hi = *(uint2*)(kp + 64);
    unsigned lol[4] = {lo.x & 0xffff, lo.x >> 16, lo.y & 0xffff, lo.y >> 16};
    unsigned hil[4] = {hi.x & 0xffff, hi.x >> 16, hi.y & 0xffff, hi.y >> 16};
    uint2 olo, ohi;
    unsigned t[4], u[4];
#pragma unroll
    for (int e = 0; e < 4; ++e) {
      const float l = bfbits2f(lol[e]), h = bfbits2f(hil[e]);
      t[e] = f2bf_bits(l * cs[e] - h * sn[e]);
      u[e] = f2bf_bits(h * cs[e] + l * sn[e]);
    }
    olo.x = t[0] | (t[1] << 16); olo.y = t[2] | (t[3] << 16);
    ohi.x = u[0] | (u[1] << 16); ohi.y = u[2] | (u[3] << 16);
    *(uint2*)kp = olo;
    *(uint2*)(kp + 64) = ohi;
  }
}

// Flash attention, 32x32x16 MFMA, single-barrier double-buffered pipeline.
// Block = 128 q x one (b,h); 4 waves, wave owns 32 q-cols.  BKV=64.
// K/V fragment-order staging (HW-verified layouts, round 4).  Q in registers.
// qt pairing (y<8 ? y : 23-y) balances per-CU work under mod-256 round-robin
// dispatch: resident pairs (qt, 15-qt) sum to 36 iters each.
__global__ __launch_bounds__(256, 2) void flash_attn(const bf16* Q,
                                                     const bf16* __restrict__ K,
                                                     const bf16* __restrict__ Vt,
                                                     bf16* O, int S) {
  __shared__ __align__(16) short lK[2][16 * 512];  // 2 x 16 KB
  __shared__ __align__(16) short lV[2][16 * 512];  // 2 x 16 KB
  __shared__ __align__(16) short lP[4 * 2048];     // 16 KB, wave-private

  const int tid = threadIdx.x;
  const int wave = tid >> 6;
  const int lane = tid & 63;
  const int l31 = lane & 31;
  const int half = lane >> 5;
  const int bh = blockIdx.x;
  const int y = blockIdx.y;
  const int qt = (y < 8) ? y : 23 - y;
  const int q0 = qt * 128;
  const int b = bh >> 4;
  const int h = bh & 15;
  const int kvh = h >> 2;
  const int wq0 = wave * 32;
  const int q_g = q0 + wq0 + l31;

  // Q fragments in registers (B-operand): qf[ks] = Q[q_g][d=ks*16+half*8+j]
  short8 qf[8];
  {
    const bf16* qbase = Q + ((size_t)(b * S + q_g) * 16 + h) * 128 + half * 8;
#pragma unroll
    for (int ks = 0; ks < 8; ++ks)
      qf[ks] = *(const short8*)(qbase + ks * 16);
  }

  floatx16 acc[4] = {};
  float m_i = -1.0e30f, l_i = 0.0f;
  const float scale = 0.08838834764831845f;
  const int fk0 = wave * 4;
  short* lPw = &lP[wave * 2048];
  const int sw = l31 & 7;
  const int niter = 2 * qt + 2;

  auto stage = [&](int buf, int kv0) {
#pragma unroll
    for (int i = 0; i < 4; ++i) {
      const int fk = fk0 + i;
      const int mt = fk & 1, kstep = fk >> 1;
      async_copy16(K + ((size_t)(b * S + kv0 + mt * 32 + l31) * 4 + kvh) * 128 + kstep * 16 + half * 8,
                   &lK[buf][fk * 512]);
      const int kvs = fk >> 2, mtd = fk & 3;
      async_copy16(Vt + ((size_t)(b * 4 + kvh) * 128 + mtd * 32 + l31) * S + kv0 + kvs * 16 + half * 8,
                   &lV[buf][fk * 512]);
    }
  };

  stage(0, 0);  // prefetch

  for (int it = 0; it < niter; ++it) {
    const int kv0 = it * 64;
    const int cur = it & 1;
    __syncthreads();  // drains DMA(cur) issued one iter ago; frees buf cur^1
    if (it + 1 < niter) stage(cur ^ 1, kv0 + 64);

    // S^T = K·Q^T  (C: col = q = l31, row = kv = mt*32 + (r&3)+8*(r>>2)+4*half)
    floatx16 st[2] = {};
#pragma unroll
    for (int ks = 0; ks < 8; ++ks) {
      short8 k0 = *(const short8*)&lK[cur][(ks * 2 + 0) * 512 + lane * 8];
      short8 k1 = *(const short8*)&lK[cur][(ks * 2 + 1) * 512 + lane * 8];
      st[0] = __builtin_amdgcn_mfma_f32_32x32x16_bf16(k0, qf[ks], st[0], 0, 0, 0);
      st[1] = __builtin_amdgcn_mfma_f32_32x32x16_bf16(k1, qf[ks], st[1], 0, 0, 0);
    }

    // scale + causal mask + per-lane softmax (1 shfl per reduction)
    float mx = -1.0e30f;
    if (kv0 + 63 > q0 + wq0) {
#pragma unroll
      for (int r = 0; r < 16; ++r) {
        const int kv_l = kv0 + (r & 3) + 8 * (r >> 2) + 4 * half;
        float v0 = st[0][r] * scale;
        v0 = (kv_l > q_g) ? -1.0e9f : v0;
        float v1 = st[1][r] * scale;
        v1 = (kv_l + 32 > q_g) ? -1.0e9f : v1;
        st[0][r] = v0; st[1][r] = v1;
        mx = fmaxf(mx, fmaxf(v0, v1));
      }
    } else {
#pragma unroll
      for (int r = 0; r < 16; ++r) {
        const float v0 = st[0][r] * scale;
        const float v1 = st[1][r] * scale;
        st[0][r] = v0; st[1][r] = v1;
        mx = fmaxf(mx, fmaxf(v0, v1));
      }
    }
    mx = fmaxf(mx, __shfl_xor(mx, 32));
    const float mnew = fmaxf(m_i, mx);
    const float alpha = __expf(m_i - mnew);
    m_i = mnew;
    float rs = 0.0f;
#pragma unroll
    for (int r = 0; r < 16; ++r) {
      const float p0 = __expf(st[0][r] - mnew);
      const float p1 = __expf(st[1][r] - mnew);
      st[0][r] = p0; st[1][r] = p1;
      rs += p0 + p1;
    }
    rs += __shfl_xor(rs, 32);
    l_i = l_i * alpha + rs;
#pragma unroll
    for (int t = 0; t < 4; ++t)
#pragma unroll
      for (int r = 0; r < 16; ++r) acc[t][r] *= alpha;

    // P -> lPw (wave-private; regs 4g..4g+3 -> kv = mt*32+8g+4*half+{0..3})
#pragma unroll
    for (int g = 0; g < 4; ++g) {
      uint2 p0, p1;
      p0.x = f2bf_bits(st[0][4 * g]) | (f2bf_bits(st[0][4 * g + 1]) << 16);
      p0.y = f2bf_bits(st[0][4 * g + 2]) | (f2bf_bits(st[0][4 * g + 3]) << 16);
      p1.x = f2bf_bits(st[1][4 * g]) | (f2bf_bits(st[1][4 * g + 1]) << 16);
      p1.y = f2bf_bits(st[1][4 * g + 2]) | (f2bf_bits(st[1][4 * g + 3]) << 16);
      *(uint2*)&lPw[l31 * 64 + (g ^ sw) * 8 + half * 4] = p0;
      *(uint2*)&lPw[l31 * 64 + ((4 + g) ^ sw) * 8 + half * 4] = p1;
    }

    // O^T += V^T·P^T  (A = V frag, B = P frag; C: col = q = l31, rows = d)
#pragma unroll
    for (int kvs = 0; kvs < 4; ++kvs) {
      const int ckr = kvs * 2 + half;
      short8 pf = *(const short8*)&lPw[l31 * 64 + (ckr ^ sw) * 8];
#pragma unroll
      for (int mtd = 0; mtd < 4; ++mtd) {
        short8 vf = *(const short8*)&lV[cur][(kvs * 4 + mtd) * 512 + lane * 8];
        acc[mtd] = __builtin_amdgcn_mfma_f32_32x32x16_bf16(vf, pf, acc[mtd], 0, 0, 0);
      }
    }
  }

  // epilogue: lane owns q-col; d rows = mtd*32 + 8g + 4*half + {0..3}
  const float inv_l = 1.0f / l_i;
  bf16* obase = O + ((size_t)(b * S + q_g) * 16 + h) * 128;
#pragma unroll
  for (int mtd = 0; mtd < 4; ++mtd)
#pragma unroll
    for (int g = 0; g < 4; ++g) {
      uint2 pk;
      pk.x = f2bf_bits(acc[mtd][4 * g] * inv_l) | (f2bf_bits(acc[mtd][4 * g + 1] * inv_l) << 16);
      pk.y = f2bf_bits(acc[mtd][4 * g + 2] * inv_l) | (f2bf_bits(acc[mtd][4 * g + 3] * inv_l) << 16);
      *(uint2*)(obase + mtd * 32 + 8 * g + 4 * half) = pk;
    }
}

extern "C" void kernel_launch(void* const* d_in, const int* in_sizes, int n_in,
                              void* d_out, int out_size, void* d_ws, size_t ws_size,
                              hipStream_t stream) {
  const void* hs = d_in[0];
  const void* wq = d_in[1];
  const void* bq = d_in[2];
  const void* wk = d_in[3];
  const void* bk = d_in[4];
  const void* wv = d_in[5];
  const void* bv = d_in[6];
  const void* wo = d_in[7];
  const int* pos = (const int*)d_in[8];

  const int S = 2048, H = 2048, KV = 512;
  const int B = in_sizes[0] / (S * H);
  const int M = B * S;

  char* ws = (char*)d_ws;
  size_t off = 0;
  auto alloc = [&](size_t bytes) { char* p = ws + off; off += (bytes + 255) & ~(size_t)255; return p; };
  bf16* hsb = (bf16*)alloc((size_t)M * H * 2);
  bf16* wqb = (bf16*)alloc((size_t)H * H * 2);
  bf16* wkb = (bf16*)alloc((size_t)KV * H * 2);
  bf16* wvb = (bf16*)alloc((size_t)KV * H * 2);
  bf16* wob = (bf16*)alloc((size_t)H * H * 2);
  bf16* bias3 = (bf16*)alloc(3072 * 2);
  bf16* Qb = (bf16*)alloc((size_t)M * H * 2);
  bf16* Kb = (bf16*)alloc((size_t)M * KV * 2);
  bf16* Vt = (bf16*)alloc((size_t)M * KV * 2);
  int* flag = (int*)alloc(256);
  bf16* AO = Qb;  // flash writes O over its own Q rows (disjoint per block)

  dtype_sniff<<<1, 256, 0, stream>>>((const unsigned int*)hs, flag);
  conv_all<<<2048, 256, 0, stream>>>(hs, wq, wk, wv, wo, bq, bk, bv,
                                     hsb, wqb, wkb, wvb, wob, bias3,
                                     (long)M * H / 4, flag);
  qkv_gemm<<<dim3(24, M / 128), 256, 0, stream>>>(hsb, wqb, wkb, wvb, bias3,
                                                  Qb, Kb, Vt, M, H, S);
  rope_kernel<<<M, 256, 0, stream>>>(Qb, Kb, pos);
  flash_attn<<<dim3(B * 16, S / 128), 256, 0, stream>>>(Qb, Kb, Vt, AO, S);
  gemm_o<<<dim3(H / 128, M / 128), 256, 0, stream>>>(AO, wob, d_out, M, H, H, flag);
}